// Round 3
// baseline (503.353 us; speedup 1.0000x reference)
//
#include <hip/hip_runtime.h>
#include <hip/hip_bf16.h>
#include <stdint.h>

#define B_ 2
#define S_ 2048
#define D_ 1024
#define H_ 16
#define HD_ 64

typedef __attribute__((ext_vector_type(8))) short short8v;
typedef __attribute__((ext_vector_type(4))) float f32x4;
typedef __attribute__((ext_vector_type(4))) int int4v;

__device__ __forceinline__ unsigned short f2bf(float f) {
  union { float f; unsigned int u; } c; c.f = f;
  unsigned int u = c.u;
  unsigned int r = u + 0x7FFFu + ((u >> 16) & 1u);
  return (unsigned short)(r >> 16);
}

// ---------------- fp32 -> bf16 convert (vectorized) ----------------
__global__ __launch_bounds__(256) void convert_f32_bf16(
    const float* __restrict__ in, unsigned short* __restrict__ out, int n4) {
  int i = blockIdx.x * 256 + threadIdx.x;
  if (i >= n4) return;
  float4 v = reinterpret_cast<const float4*>(in)[i];
  ushort4 o;
  o.x = f2bf(v.x); o.y = f2bf(v.y); o.z = f2bf(v.z); o.w = f2bf(v.w);
  reinterpret_cast<ushort4*>(out)[i] = o;
}

// ---------------- GEMM (A[M][K] @ B[N][K]^T + bias), 128x128 tile ----------------
template<bool OUT_BF16>
__global__ __launch_bounds__(256) void gemm_bt(
    const unsigned short* __restrict__ A,   // [M][K] bf16
    const unsigned short* __restrict__ Bm,  // [N][K] bf16
    const float* __restrict__ bias,         // [N]
    void* __restrict__ Cout,                // [M][N]
    int M, int N, int K)
{
  __shared__ unsigned short As[128 * 40];
  __shared__ unsigned short Bs[128 * 40];
  const int tid = threadIdx.x;
  const int bM = blockIdx.y * 128, bN = blockIdx.x * 128;
  const int lane = tid & 63;
  const int wr = ((tid >> 7) & 1) * 64;   // wave row
  const int wc = ((tid >> 6) & 1) * 64;   // wave col
  const int lr = lane & 15, lk = (lane >> 4) * 8;
  const int srow = tid >> 1, skk = (tid & 1) * 16;

  f32x4 acc[4][4] = {};

  const size_t aBase = (size_t)(bM + srow) * K;
  const size_t bBase = (size_t)(bN + srow) * K;

  for (int k0 = 0; k0 < K; k0 += 32) {
    const int4v* asrc = reinterpret_cast<const int4v*>(A + aBase + k0 + skk);
    int4v* adst = reinterpret_cast<int4v*>(&As[srow * 40 + skk]);
    adst[0] = asrc[0]; adst[1] = asrc[1];
    const int4v* bsrc = reinterpret_cast<const int4v*>(Bm + bBase + k0 + skk);
    int4v* bdst = reinterpret_cast<int4v*>(&Bs[srow * 40 + skk]);
    bdst[0] = bsrc[0]; bdst[1] = bsrc[1];
    __syncthreads();
    short8v av[4], bv[4];
#pragma unroll
    for (int m = 0; m < 4; m++)
      av[m] = *reinterpret_cast<const short8v*>(&As[(wr + m * 16 + lr) * 40 + lk]);
#pragma unroll
    for (int n = 0; n < 4; n++)
      bv[n] = *reinterpret_cast<const short8v*>(&Bs[(wc + n * 16 + lr) * 40 + lk]);
#pragma unroll
    for (int m = 0; m < 4; m++)
#pragma unroll
      for (int n = 0; n < 4; n++)
        acc[m][n] = __builtin_amdgcn_mfma_f32_16x16x32_bf16(av[m], bv[n], acc[m][n], 0, 0, 0);
    __syncthreads();
  }

  const int r0 = wr + (lane >> 4) * 4;
  const int c0 = wc + lr;
#pragma unroll
  for (int m = 0; m < 4; m++) {
#pragma unroll
    for (int n = 0; n < 4; n++) {
      const int gc = bN + c0 + n * 16;
      const float bb = bias[gc];
#pragma unroll
      for (int j = 0; j < 4; j++) {
        const int gr = bM + r0 + m * 16 + j;
        float v = acc[m][n][j] + bb;
        if (OUT_BF16)
          reinterpret_cast<unsigned short*>(Cout)[(size_t)gr * N + gc] = f2bf(v);
        else
          reinterpret_cast<float*>(Cout)[(size_t)gr * N + gc] = v;
      }
    }
  }
}

// ---------------- per-head transpose: xp[B*S][D] -> xhT[(b*H+h)*64+d][S] ----------------
__global__ __launch_bounds__(256) void transpose_heads(
    const unsigned short* __restrict__ xp,
    unsigned short* __restrict__ xhT)
{
  const int bh = blockIdx.y;          // b*H + h
  const int t0 = blockIdx.x * 64;
  const int b = bh >> 4, h = bh & 15;
  __shared__ unsigned short tile[64][72];
  const int tid = threadIdx.x;
  const int c8 = (tid & 7) * 8;
  const int r = tid >> 3;             // 0..31
  const size_t inBase = ((size_t)(b * S_ + t0)) * D_ + h * HD_;
#pragma unroll
  for (int p = 0; p < 2; p++) {
    const int tt = r + p * 32;
    *reinterpret_cast<int4v*>(&tile[tt][c8]) =
        *reinterpret_cast<const int4v*>(&xp[inBase + (size_t)tt * D_ + c8]);
  }
  __syncthreads();
#pragma unroll
  for (int p = 0; p < 2; p++) {
    const int d = r + p * 32;
    short8v v;
#pragma unroll
    for (int i = 0; i < 8; i++) v[i] = (short)tile[c8 + i][d];
    *reinterpret_cast<short8v*>(&xhT[((size_t)(bh * HD_) + d) * S_ + t0 + c8]) = v;
  }
}

// ---------------- causal per-head mix: mixed = tril(Wm[h]) @ xhT^T ----------------
__global__ __launch_bounds__(256) void gemm_mix(
    const float* __restrict__ Wmix,          // [H][S][S] fp32
    const unsigned short* __restrict__ xhT,  // [B*H*HD][S] bf16
    unsigned short* __restrict__ mixed)      // [B*S][D] bf16
{
  __shared__ unsigned short As[128 * 40];
  __shared__ unsigned short Bs[128 * 40];
  const int tid = threadIdx.x;
  const int h = blockIdx.y;
  const int T0 = blockIdx.x * 128;
  const int lane = tid & 63;
  const int wr = ((tid >> 7) & 1) * 64;
  const int wc = ((tid >> 6) & 1) * 64;
  const int lr = lane & 15, lk = (lane >> 4) * 8;
  const int srow = tid >> 1, skk = (tid & 1) * 16;

  f32x4 acc[4][4] = {};

  const int t = T0 + srow;                        // A stage row (query pos)
  const float* aRow = Wmix + ((size_t)h * S_ + t) * S_;
  const int c = srow;                             // B stage row (output col)
  const int brow = ((c >> 6) * H_ + h) * HD_ + (c & 63);
  const unsigned short* bRow = xhT + (size_t)brow * S_;

  const int kMax = T0 + 128;                      // causal: skip j-tiles above diagonal
  for (int k0 = 0; k0 < kMax; k0 += 32) {
    union { unsigned short s[16]; int4v v[2]; } tmp;
#pragma unroll
    for (int q = 0; q < 4; q++) {
      float4 v = reinterpret_cast<const float4*>(aRow + k0 + skk)[q];
      const int jb = k0 + skk + q * 4;
      tmp.s[q * 4 + 0] = (jb + 0 <= t) ? f2bf(v.x) : (unsigned short)0;
      tmp.s[q * 4 + 1] = (jb + 1 <= t) ? f2bf(v.y) : (unsigned short)0;
      tmp.s[q * 4 + 2] = (jb + 2 <= t) ? f2bf(v.z) : (unsigned short)0;
      tmp.s[q * 4 + 3] = (jb + 3 <= t) ? f2bf(v.w) : (unsigned short)0;
    }
    int4v* adst = reinterpret_cast<int4v*>(&As[srow * 40 + skk]);
    adst[0] = tmp.v[0]; adst[1] = tmp.v[1];
    const int4v* bsrc = reinterpret_cast<const int4v*>(bRow + k0 + skk);
    int4v* bdst = reinterpret_cast<int4v*>(&Bs[srow * 40 + skk]);
    bdst[0] = bsrc[0]; bdst[1] = bsrc[1];
    __syncthreads();
    short8v av[4], bv[4];
#pragma unroll
    for (int m = 0; m < 4; m++)
      av[m] = *reinterpret_cast<const short8v*>(&As[(wr + m * 16 + lr) * 40 + lk]);
#pragma unroll
    for (int n = 0; n < 4; n++)
      bv[n] = *reinterpret_cast<const short8v*>(&Bs[(wc + n * 16 + lr) * 40 + lk]);
#pragma unroll
    for (int m = 0; m < 4; m++)
#pragma unroll
      for (int n = 0; n < 4; n++)
        acc[m][n] = __builtin_amdgcn_mfma_f32_16x16x32_bf16(av[m], bv[n], acc[m][n], 0, 0, 0);
    __syncthreads();
  }

  const int r0 = wr + (lane >> 4) * 4;
  const int c0 = wc + lr;
#pragma unroll
  for (int m = 0; m < 4; m++)
#pragma unroll
    for (int n = 0; n < 4; n++) {
      const int cc = c0 + n * 16;
      const int bb = cc >> 6, dd = cc & 63;
#pragma unroll
      for (int j = 0; j < 4; j++) {
        const int tt = T0 + r0 + m * 16 + j;
        mixed[((size_t)(bb * S_ + tt)) * D_ + h * HD_ + dd] = f2bf(acc[m][n][j]);
      }
    }
}

extern "C" void kernel_launch(void* const* d_in, const int* in_sizes, int n_in,
                              void* d_out, int out_size, void* d_ws, size_t ws_size,
                              hipStream_t stream) {
  const float* x     = (const float*)d_in[0];
  const float* W_in  = (const float*)d_in[1];
  const float* b_in  = (const float*)d_in[2];
  const float* W_mix = (const float*)d_in[3];
  const float* W_out = (const float*)d_in[4];
  const float* b_out = (const float*)d_in[5];

  char* ws = (char*)d_ws;
  // buf0 (8MB): xb, later reused as xhT. buf1 (8MB): xp, later reused as mixed.
  unsigned short* xb    = (unsigned short*)(ws);
  unsigned short* xp    = (unsigned short*)(ws + 8u * 1024u * 1024u);
  unsigned short* wib   = (unsigned short*)(ws + 16u * 1024u * 1024u);
  unsigned short* wob   = (unsigned short*)(ws + 18u * 1024u * 1024u);
  unsigned short* xhT   = xb;
  unsigned short* mixed = xp;

  const int nX = B_ * S_ * D_ / 4;   // 1M float4 groups
  const int nW = D_ * D_ / 4;
  convert_f32_bf16<<<dim3((nX + 255) / 256), dim3(256), 0, stream>>>(x, xb, nX);
  convert_f32_bf16<<<dim3((nW + 255) / 256), dim3(256), 0, stream>>>(W_in, wib, nW);
  convert_f32_bf16<<<dim3((nW + 255) / 256), dim3(256), 0, stream>>>(W_out, wob, nW);

  gemm_bt<true><<<dim3(D_ / 128, B_ * S_ / 128), dim3(256), 0, stream>>>(
      xb, wib, b_in, (void*)xp, B_ * S_, D_, D_);

  transpose_heads<<<dim3(S_ / 64, B_ * H_), dim3(256), 0, stream>>>(xp, xhT);

  gemm_mix<<<dim3(S_ / 128, H_), dim3(256), 0, stream>>>(W_mix, xhT, mixed);

  gemm_bt<false><<<dim3(D_ / 128, B_ * S_ / 128), dim3(256), 0, stream>>>(
      mixed, wob, b_out, (void*)d_out, B_ * S_, D_, D_);
}

// Round 4
// 471.645 us; speedup vs baseline: 1.0672x; 1.0672x over previous
//
#include <hip/hip_runtime.h>
#include <hip/hip_bf16.h>
#include <stdint.h>

#define B_ 2
#define S_ 2048
#define D_ 1024
#define H_ 16
#define HD_ 64

typedef __attribute__((ext_vector_type(8))) short short8v;
typedef __attribute__((ext_vector_type(4))) float f32x4;
typedef __attribute__((ext_vector_type(4))) int int4v;

__device__ __forceinline__ unsigned short f2bf(float f) {
  union { float f; unsigned int u; } c; c.f = f;
  unsigned int u = c.u;
  unsigned int r = u + 0x7FFFu + ((u >> 16) & 1u);
  return (unsigned short)(r >> 16);
}

// async global->LDS, 16B per lane. lds dest must be linear wavebase + lane*16.
__device__ __forceinline__ void gload16(const void* g, void* l) {
  __builtin_amdgcn_global_load_lds(
      (const __attribute__((address_space(1))) unsigned int*)g,
      (__attribute__((address_space(3))) unsigned int*)l, 16, 0, 0);
}

// ---------------- fused fp32 -> bf16 converts (x, W_in, W_out) ----------------
#define NX4_ (B_ * S_ * D_ / 4)     // 1048576 float4 groups
#define NW4_ (D_ * D_ / 4)          // 262144
__global__ __launch_bounds__(256) void convert3(
    const float* __restrict__ x, const float* __restrict__ wi, const float* __restrict__ wo,
    unsigned short* __restrict__ xb, unsigned short* __restrict__ wib,
    unsigned short* __restrict__ wob) {
  int i = blockIdx.x * 256 + threadIdx.x;
  const float* src; unsigned short* dst; int j;
  if (i < NX4_)              { src = x;  dst = xb;  j = i; }
  else if (i < NX4_ + NW4_)  { src = wi; dst = wib; j = i - NX4_; }
  else                       { src = wo; dst = wob; j = i - NX4_ - NW4_; }
  float4 v = reinterpret_cast<const float4*>(src)[j];
  ushort4 o;
  o.x = f2bf(v.x); o.y = f2bf(v.y); o.z = f2bf(v.z); o.w = f2bf(v.w);
  reinterpret_cast<ushort4*>(dst)[j] = o;
}

// ------------- GEMM (A[M][K] @ B[N][K]^T + bias), 128x128, global_load_lds -------------
template<bool OUT_BF16>
__global__ __launch_bounds__(256) void gemm_bt(
    const unsigned short* __restrict__ A,   // [M][K] bf16
    const unsigned short* __restrict__ Bm,  // [N][K] bf16
    const float* __restrict__ bias,         // [N]
    void* __restrict__ Cout,                // [M][N]
    int M, int N, int K)
{
  __shared__ unsigned short As[128 * 32];   // linear, required by global_load_lds
  __shared__ unsigned short Bs[128 * 32];
  const int tid = threadIdx.x;
  const int bM = blockIdx.y * 128, bN = blockIdx.x * 128;
  const int lane = tid & 63;
  const int w = tid >> 6;                  // wave 0..3
  const int wr = (w >> 1) * 64;            // wave row quadrant
  const int wc = (w & 1) * 64;             // wave col quadrant
  const int lr = lane & 15, lk = (lane >> 4) * 8;
  // staging coords: per wave-issue 1KB = 16 rows of 64B
  const int srA = w * 32 + (lane >> 2);    // +16 for issue 1
  const int scs = (lane & 3) * 8;

  f32x4 acc[4][4] = {};

  for (int k0 = 0; k0 < K; k0 += 32) {
    gload16(A + (size_t)(bM + srA) * K + k0 + scs,      &As[srA * 32 + scs]);
    gload16(A + (size_t)(bM + srA + 16) * K + k0 + scs, &As[(srA + 16) * 32 + scs]);
    gload16(Bm + (size_t)(bN + srA) * K + k0 + scs,      &Bs[srA * 32 + scs]);
    gload16(Bm + (size_t)(bN + srA + 16) * K + k0 + scs, &Bs[(srA + 16) * 32 + scs]);
    __syncthreads();
    short8v av[4], bv[4];
#pragma unroll
    for (int m = 0; m < 4; m++)
      av[m] = *reinterpret_cast<const short8v*>(&As[(wr + m * 16 + lr) * 32 + lk]);
#pragma unroll
    for (int n = 0; n < 4; n++)
      bv[n] = *reinterpret_cast<const short8v*>(&Bs[(wc + n * 16 + lr) * 32 + lk]);
#pragma unroll
    for (int m = 0; m < 4; m++)
#pragma unroll
      for (int n = 0; n < 4; n++)
        acc[m][n] = __builtin_amdgcn_mfma_f32_16x16x32_bf16(av[m], bv[n], acc[m][n], 0, 0, 0);
    __syncthreads();
  }

  const int r0 = wr + (lane >> 4) * 4;
  const int c0 = wc + lr;
#pragma unroll
  for (int m = 0; m < 4; m++) {
#pragma unroll
    for (int n = 0; n < 4; n++) {
      const int gc = bN + c0 + n * 16;
      const float bb = bias[gc];
#pragma unroll
      for (int j = 0; j < 4; j++) {
        const int gr = bM + r0 + m * 16 + j;
        float v = acc[m][n][j] + bb;
        if (OUT_BF16)
          reinterpret_cast<unsigned short*>(Cout)[(size_t)gr * N + gc] = f2bf(v);
        else
          reinterpret_cast<float*>(Cout)[(size_t)gr * N + gc] = v;
      }
    }
  }
}

// ---------------- per-head transpose: xp[B*S][D] -> xhT[(b*H+h)*64+d][S] ----------------
__global__ __launch_bounds__(256) void transpose_heads(
    const unsigned short* __restrict__ xp,
    unsigned short* __restrict__ xhT)
{
  const int bh = blockIdx.y;          // b*H + h
  const int t0 = blockIdx.x * 64;
  const int b = bh >> 4, h = bh & 15;
  __shared__ unsigned short tile[64][72];
  const int tid = threadIdx.x;
  const int c8 = (tid & 7) * 8;
  const int r = tid >> 3;             // 0..31
  const size_t inBase = ((size_t)(b * S_ + t0)) * D_ + h * HD_;
#pragma unroll
  for (int p = 0; p < 2; p++) {
    const int tt = r + p * 32;
    *reinterpret_cast<int4v*>(&tile[tt][c8]) =
        *reinterpret_cast<const int4v*>(&xp[inBase + (size_t)tt * D_ + c8]);
  }
  __syncthreads();
#pragma unroll
  for (int p = 0; p < 2; p++) {
    const int d = r + p * 32;
    short8v v;
#pragma unroll
    for (int i = 0; i < 8; i++) v[i] = (short)tile[c8 + i][d];
    *reinterpret_cast<short8v*>(&xhT[((size_t)(bh * HD_) + d) * S_ + t0 + c8]) = v;
  }
}

// ---------------- causal per-head mix, 64-row tiles ----------------
template<bool MASK>
__device__ __forceinline__ short8v mix_fragA(const float* Asf, int rl, int lk, int k0, int T0) {
  f32x4 f0 = *reinterpret_cast<const f32x4*>(&Asf[rl * 32 + lk]);
  f32x4 f1 = *reinterpret_cast<const f32x4*>(&Asf[rl * 32 + lk + 4]);
  const int t = T0 + rl;
  short8v a;
#pragma unroll
  for (int e = 0; e < 4; e++) {
    float v0 = f0[e], v1 = f1[e];
    if (MASK) {
      if (k0 + lk + e > t)     v0 = 0.0f;
      if (k0 + lk + 4 + e > t) v1 = 0.0f;
    }
    a[e]     = (short)f2bf(v0);
    a[4 + e] = (short)f2bf(v1);
  }
  return a;
}

template<bool MASK>
__device__ __forceinline__ void mix_step(
    const float* Asf, const unsigned short* Bs, f32x4 (&acc)[2][4],
    int wr, int wc, int lr, int lk, int k0, int T0) {
  short8v av[2], bv[4];
#pragma unroll
  for (int m = 0; m < 2; m++)
    av[m] = mix_fragA<MASK>(Asf, wr + m * 16 + lr, lk, k0, T0);
#pragma unroll
  for (int n = 0; n < 4; n++)
    bv[n] = *reinterpret_cast<const short8v*>(&Bs[(wc + n * 16 + lr) * 32 + lk]);
#pragma unroll
  for (int m = 0; m < 2; m++)
#pragma unroll
    for (int n = 0; n < 4; n++)
      acc[m][n] = __builtin_amdgcn_mfma_f32_16x16x32_bf16(av[m], bv[n], acc[m][n], 0, 0, 0);
}

__global__ __launch_bounds__(256) void gemm_mix(
    const float* __restrict__ Wmix,          // [H][S][S] fp32
    const unsigned short* __restrict__ xhT,  // [B*H*HD][S] bf16
    unsigned short* __restrict__ mixed)      // [B*S][D] bf16
{
  __shared__ float Asf[64 * 32];            // fp32 W tile, 8KB
  __shared__ unsigned short Bs[128 * 32];   // bf16 x tile, 8KB
  const int tid = threadIdx.x;
  const int h = blockIdx.y;
  const int xi = blockIdx.x;                // interleave long/short tiles in dispatch order
  const int tilei = (xi & 1) ? (31 - (xi >> 1)) : (xi >> 1);
  const int T0 = tilei * 64;
  const int lane = tid & 63;
  const int w = tid >> 6;
  const int wr = (w >> 1) * 32;
  const int wc = (w & 1) * 64;
  const int lr = lane & 15, lk = (lane >> 4) * 8;
  // A staging: 8 issues of 1KB (8 fp32 rows each); wave w does issues {2w, 2w+1}
  const int arA = w * 16 + (lane >> 3);     // +8 for issue 1
  const int acf = (lane & 7) * 4;
  // B staging: 8 issues of 1KB (16 bf16 rows each)
  const int brA = w * 32 + (lane >> 2);     // +16 for issue 1
  const int bcs = (lane & 3) * 8;
  const int br0 = ((brA >> 6) * H_ + h) * HD_ + (brA & 63);
  const int br1 = (((brA + 16) >> 6) * H_ + h) * HD_ + ((brA + 16) & 63);

  f32x4 acc[2][4] = {};
  const float* Wh = Wmix + (size_t)h * S_ * S_;

  const int kMax = T0 + 64;
  for (int k0 = 0; k0 < kMax; k0 += 32) {
    gload16(Wh + (size_t)(T0 + arA) * S_ + k0 + acf,     &Asf[arA * 32 + acf]);
    gload16(Wh + (size_t)(T0 + arA + 8) * S_ + k0 + acf, &Asf[(arA + 8) * 32 + acf]);
    gload16(xhT + (size_t)br0 * S_ + k0 + bcs, &Bs[brA * 32 + bcs]);
    gload16(xhT + (size_t)br1 * S_ + k0 + bcs, &Bs[(brA + 16) * 32 + bcs]);
    __syncthreads();
    if (k0 + 32 > T0)
      mix_step<true>(Asf, Bs, acc, wr, wc, lr, lk, k0, T0);
    else
      mix_step<false>(Asf, Bs, acc, wr, wc, lr, lk, k0, T0);
    __syncthreads();
  }

  const int r0 = wr + (lane >> 4) * 4;
  const int c0 = wc + lr;
#pragma unroll
  for (int m = 0; m < 2; m++)
#pragma unroll
    for (int n = 0; n < 4; n++) {
      const int cc = c0 + n * 16;
      const int bb = cc >> 6, dd = cc & 63;
#pragma unroll
      for (int j = 0; j < 4; j++) {
        const int tt = T0 + r0 + m * 16 + j;
        mixed[((size_t)(bb * S_ + tt)) * D_ + h * HD_ + dd] = f2bf(acc[m][n][j]);
      }
    }
}

extern "C" void kernel_launch(void* const* d_in, const int* in_sizes, int n_in,
                              void* d_out, int out_size, void* d_ws, size_t ws_size,
                              hipStream_t stream) {
  const float* x     = (const float*)d_in[0];
  const float* W_in  = (const float*)d_in[1];
  const float* b_in  = (const float*)d_in[2];
  const float* W_mix = (const float*)d_in[3];
  const float* W_out = (const float*)d_in[4];
  const float* b_out = (const float*)d_in[5];

  char* ws = (char*)d_ws;
  unsigned short* xb    = (unsigned short*)(ws);                          // 8MB, reused as xhT
  unsigned short* xp    = (unsigned short*)(ws + 8u * 1024u * 1024u);     // 8MB, reused as mixed
  unsigned short* wib   = (unsigned short*)(ws + 16u * 1024u * 1024u);    // 2MB
  unsigned short* wob   = (unsigned short*)(ws + 18u * 1024u * 1024u);    // 2MB
  unsigned short* xhT   = xb;
  unsigned short* mixed = xp;

  convert3<<<dim3((NX4_ + 2 * NW4_) / 256), dim3(256), 0, stream>>>(
      x, W_in, W_out, xb, wib, wob);

  gemm_bt<true><<<dim3(D_ / 128, B_ * S_ / 128), dim3(256), 0, stream>>>(
      xb, wib, b_in, (void*)xp, B_ * S_, D_, D_);

  transpose_heads<<<dim3(S_ / 64, B_ * H_), dim3(256), 0, stream>>>(xp, xhT);

  gemm_mix<<<dim3(S_ / 64, H_), dim3(256), 0, stream>>>(W_mix, xhT, mixed);

  gemm_bt<false><<<dim3(D_ / 128, B_ * S_ / 128), dim3(256), 0, stream>>>(
      mixed, wob, b_out, (void*)d_out, B_ * S_, D_, D_);
}